// Round 1
// baseline (337.176 us; speedup 1.0000x reference)
//
#include <hip/hip_runtime.h>

#define RTOT 12960      // 4 * 3240 rows
#define PAIRS 3240
#define NB_VAR 81
#define HID 256
#define EPS 1e-5f

// ---------------- pair table + zero stats ----------------
__global__ void k_misc(int2* __restrict__ pairs, float* __restrict__ stats) {
    int idx = blockIdx.x * blockDim.x + threadIdx.x;
    if (idx < 5 * 512) stats[idx] = 0.f;
    if (idx < PAIRS) {
        int p = idx, i = 0, off = 0;
        while (off + (NB_VAR - 1 - i) <= p) { off += NB_VAR - 1 - i; i++; }
        int j = i + 1 + (p - off);
        pairs[idx] = make_int2(i, j);
    }
}

// ---------------- zero diagonal blocks of output ----------------
__global__ void k_zero_diag(float* __restrict__ out) {
    int idx = blockIdx.x * blockDim.x + threadIdx.x;
    if (idx >= 4 * NB_VAR * 81) return;
    int b = idx / (NB_VAR * 81);
    int rem = idx - b * (NB_VAR * 81);
    int i = rem / 81;
    int t = rem - i * 81;
    out[((b * NB_VAR + i) * NB_VAR + i) * 81 + t] = 0.f;
}

// ---------------- input projection: h0 = relu(rr @ w_in.T + b_in) ----------------
__global__ void k_in(const float* __restrict__ x, const float* __restrict__ w_in,
                     const float* __restrict__ b_in, const int2* __restrict__ pairs,
                     float* __restrict__ h0) {
    int r = blockIdx.x;
    int c = threadIdx.x;
    int b = r / PAIRS;
    int p = r - b * PAIRS;
    int2 ij = pairs[p];
    const float* xb = x + b * NB_VAR * 2;
    float f0 = xb[ij.x * 2 + 0], f1 = xb[ij.x * 2 + 1];
    float f2 = xb[ij.y * 2 + 0], f3 = xb[ij.y * 2 + 1];
    float4 w = ((const float4*)w_in)[c];
    float v = f0 * w.x + f1 * w.y + f2 * w.z + f3 * w.w + b_in[c];
    h0[r * HID + c] = fmaxf(v, 0.f);
}

// ---------------- column stats (sum, sumsq) of R x 256 matrix ----------------
__global__ void k_stats(const float* __restrict__ X, float* __restrict__ st) {
    int c = threadIdx.x;
    int rpb = (RTOT + gridDim.x - 1) / gridDim.x;
    int r0 = blockIdx.x * rpb;
    int r1 = min(r0 + rpb, RTOT);
    float s = 0.f, s2 = 0.f;
    for (int r = r0; r < r1; r++) {
        float v = X[r * HID + c];
        s += v; s2 += v * v;
    }
    atomicAdd(&st[c], s);
    atomicAdd(&st[HID + c], s2);
}

// ---------------- GEMM: Y = relu(bn(X)) @ W.T + bias (+res) ----------------
// X: R x 256 (raw, pre-BN). W: N x 256 row-major. Y: R x N.
#define BM 64
#define BN 64
#define BK 32
#define LDT 68   // padded LDS stride (floats): 68%4==0 keeps float4 align, breaks bank aliasing

__global__ __launch_bounds__(256) void k_gemm(
        const float* __restrict__ X, const float* __restrict__ st,
        const float* __restrict__ g, const float* __restrict__ beta,
        const float* __restrict__ W, const float* __restrict__ bias,
        const float* __restrict__ res, float* __restrict__ Y, int N) {
    __shared__ float sA[BK][LDT];
    __shared__ float sB[BK][LDT];
    __shared__ float sS[HID], sT[HID];
    int tid = threadIdx.x;
    {
        float sum = st[tid], sq = st[HID + tid];
        float m = sum * (1.f / RTOT);
        float v = sq * (1.f / RTOT) - m * m;
        float sc = g[tid] * rsqrtf(v + EPS);
        sS[tid] = sc;
        sT[tid] = beta[tid] - m * sc;
    }
    __syncthreads();

    int bm0 = blockIdx.x * BM;
    int bn0 = blockIdx.y * BN;
    int ty = tid >> 4, tx = tid & 15;
    float acc[4][4] = {};

    for (int k0 = 0; k0 < HID; k0 += BK) {
#pragma unroll
        for (int l = 0; l < 2; l++) {
            int lin = tid + l * 256;
            int row = lin >> 3;
            int c4 = lin & 7;
            int gk = k0 + c4 * 4;
            int gr = bm0 + row;
            int gra = (gr < RTOT) ? gr : 0;
            float4 a = *(const float4*)(X + (size_t)gra * HID + gk);
            a.x = fmaxf(a.x * sS[gk + 0] + sT[gk + 0], 0.f);
            a.y = fmaxf(a.y * sS[gk + 1] + sT[gk + 1], 0.f);
            a.z = fmaxf(a.z * sS[gk + 2] + sT[gk + 2], 0.f);
            a.w = fmaxf(a.w * sS[gk + 3] + sT[gk + 3], 0.f);
            sA[c4 * 4 + 0][row] = a.x;
            sA[c4 * 4 + 1][row] = a.y;
            sA[c4 * 4 + 2][row] = a.z;
            sA[c4 * 4 + 3][row] = a.w;
            int gn = bn0 + row;
            int gna = (gn < N) ? gn : 0;
            float4 bv = *(const float4*)(W + (size_t)gna * HID + gk);
            sB[c4 * 4 + 0][row] = bv.x;
            sB[c4 * 4 + 1][row] = bv.y;
            sB[c4 * 4 + 2][row] = bv.z;
            sB[c4 * 4 + 3][row] = bv.w;
        }
        __syncthreads();
#pragma unroll
        for (int kk = 0; kk < BK; kk++) {
            float av[4], bv[4];
            *(float4*)av = *(const float4*)&sA[kk][ty * 4];
            *(float4*)bv = *(const float4*)&sB[kk][tx * 4];
#pragma unroll
            for (int i = 0; i < 4; i++)
#pragma unroll
                for (int j = 0; j < 4; j++)
                    acc[i][j] = fmaf(av[i], bv[j], acc[i][j]);
        }
        __syncthreads();
    }

#pragma unroll
    for (int i = 0; i < 4; i++) {
        int gr = bm0 + ty * 4 + i;
        if (gr >= RTOT) continue;
#pragma unroll
        for (int j = 0; j < 4; j++) {
            int gn = bn0 + tx * 4 + j;
            if (gn >= N) continue;
            float v = acc[i][j] + bias[gn];
            if (res) v += res[(size_t)gr * N + gn];
            Y[(size_t)gr * N + gn] = v;
        }
    }
}

// ---------------- symmetric scatter ----------------
__global__ void k_scatter(const float* __restrict__ pred, const int2* __restrict__ pairs,
                          float* __restrict__ out) {
    int idx = blockIdx.x * blockDim.x + threadIdx.x;
    if (idx >= RTOT * 81) return;
    int r = idx / 81;
    int t = idx - r * 81;
    int b = r / PAIRS;
    int p = r - b * PAIRS;
    int2 ij = pairs[p];
    int gi = t / 9, gj = t - gi * 9;
    float v = pred[idx];
    out[((b * NB_VAR + ij.x) * NB_VAR + ij.y) * 81 + t] = v;
    out[((b * NB_VAR + ij.y) * NB_VAR + ij.x) * 81 + gj * 9 + gi] = v;
}

extern "C" void kernel_launch(void* const* d_in, const int* in_sizes, int n_in,
                              void* d_out, int out_size, void* d_ws, size_t ws_size,
                              hipStream_t stream) {
    const float* x     = (const float*)d_in[0];
    const float* w_in  = (const float*)d_in[1];
    const float* b_in  = (const float*)d_in[2];
    const float* g1    = (const float*)d_in[3];
    const float* beta1 = (const float*)d_in[4];
    const float* w1    = (const float*)d_in[5];
    const float* bias1 = (const float*)d_in[6];
    const float* g2    = (const float*)d_in[7];
    const float* beta2 = (const float*)d_in[8];
    const float* w2    = (const float*)d_in[9];
    const float* bias2 = (const float*)d_in[10];
    const float* fg    = (const float*)d_in[11];
    const float* fbeta = (const float*)d_in[12];
    const float* w_out = (const float*)d_in[13];
    const float* b_out = (const float*)d_in[14];
    float* out = (float*)d_out;

    float* buf0  = (float*)d_ws;
    float* buf1  = buf0 + (size_t)RTOT * HID;
    float* buf2  = buf1 + (size_t)RTOT * HID;
    float* pred  = buf2 + (size_t)RTOT * HID;
    float* stats = pred + (size_t)RTOT * 81;
    int2*  pairs = (int2*)(stats + 5 * 512);

    k_zero_diag<<<(4 * NB_VAR * 81 + 255) / 256, 256, 0, stream>>>(out);
    k_misc<<<13, 256, 0, stream>>>(pairs, stats);
    k_in<<<RTOT, 256, 0, stream>>>(x, w_in, b_in, pairs, buf0);

    dim3 g256((RTOT + BM - 1) / BM, HID / BN);
    dim3 g81((RTOT + BM - 1) / BM, 2);

    k_stats<<<128, 256, 0, stream>>>(buf0, stats + 0 * 512);
    k_gemm<<<g256, 256, 0, stream>>>(buf0, stats + 0 * 512, g1, beta1, w1, bias1, nullptr, buf1, HID);
    k_stats<<<128, 256, 0, stream>>>(buf1, stats + 1 * 512);
    k_gemm<<<g256, 256, 0, stream>>>(buf1, stats + 1 * 512, g2, beta2, w2, bias2, buf0, buf2, HID);
    k_stats<<<128, 256, 0, stream>>>(buf2, stats + 2 * 512);
    k_gemm<<<g256, 256, 0, stream>>>(buf2, stats + 2 * 512, g1 + HID, beta1 + HID, w1 + HID * HID, bias1 + HID, nullptr, buf1, HID);
    k_stats<<<128, 256, 0, stream>>>(buf1, stats + 3 * 512);
    k_gemm<<<g256, 256, 0, stream>>>(buf1, stats + 3 * 512, g2 + HID, beta2 + HID, w2 + HID * HID, bias2 + HID, buf2, buf0, HID);
    k_stats<<<128, 256, 0, stream>>>(buf0, stats + 4 * 512);
    k_gemm<<<g81, 256, 0, stream>>>(buf0, stats + 4 * 512, fg, fbeta, w_out, b_out, nullptr, pred, 81);

    k_scatter<<<(RTOT * 81 + 255) / 256, 256, 0, stream>>>(pred, pairs, out);
}

// Round 2
// 156.002 us; speedup vs baseline: 2.1614x; 2.1614x over previous
//
#include <hip/hip_runtime.h>

#define RTOT 12960      // 4 * 3240 rows
#define PAIRS 3240
#define NB_VAR 81
#define HID 256
#define EPS 1e-5f

#define BM 128
#define BN 64
#define BK 32
#define LDST 40   // LDS row stride in bf16 elems (80 B): rows r,r+8 alias -> 2-way (free)

using bf8   = __attribute__((ext_vector_type(8))) short;
using f32x4 = __attribute__((ext_vector_type(4))) float;

__device__ inline ushort f2bf(float f) {
    union { float f; unsigned u; } c; c.f = f;
    unsigned u = c.u + 0x7fffu + ((c.u >> 16) & 1u);
    return (ushort)(u >> 16);
}
__device__ inline unsigned pk2(float a, float b) {
    return (unsigned)f2bf(a) | ((unsigned)f2bf(b) << 16);
}

// ---------------- pairs + zero stats + zero diagonal of out ----------------
__global__ void k_misc(int2* __restrict__ pairs, float* __restrict__ stats,
                       float* __restrict__ out) {
    int idx = blockIdx.x * blockDim.x + threadIdx.x;
    if (idx < 5 * 512) stats[idx] = 0.f;
    if (idx < PAIRS) {
        int p = idx, i = 0, off = 0;
        while (off + (NB_VAR - 1 - i) <= p) { off += NB_VAR - 1 - i; i++; }
        pairs[idx] = make_int2(i, i + 1 + (p - off));
    }
    if (idx < 4 * NB_VAR * 81) {
        int b = idx / (NB_VAR * 81);
        int rem = idx - b * (NB_VAR * 81);
        int i = rem / 81, t = rem - i * 81;
        out[((size_t)(b * NB_VAR + i) * NB_VAR + i) * 81 + t] = 0.f;
    }
}

// ---------------- fp32 -> bf16 weight conversion ----------------
// layout in wbf: [w1_0 | w1_1 | w2_0 | w2_1 | w_out]
__global__ void k_wconv(const float* __restrict__ w1, const float* __restrict__ w2,
                        const float* __restrict__ w_out, ushort* __restrict__ wbf) {
    int idx = blockIdx.x * blockDim.x + threadIdx.x;
    float v;
    if (idx < 131072)        v = w1[idx];
    else if (idx < 262144)   v = w2[idx - 131072];
    else if (idx < 262144 + 81 * 256) v = w_out[idx - 262144];
    else return;
    wbf[idx] = f2bf(v);
}

// ---------------- input proj + stage-0 stats ----------------
// 240 blocks x 54 rows each
__global__ __launch_bounds__(256) void k_in(
        const float* __restrict__ x, const float* __restrict__ w_in,
        const float* __restrict__ b_in, const int2* __restrict__ pairs,
        float* __restrict__ h0, float* __restrict__ st) {
    __shared__ float feat[54][4];
    int tid = threadIdx.x;
    int r0 = blockIdx.x * 54;
    if (tid < 54) {
        int r = r0 + tid;
        int b = r / PAIRS, p = r - b * PAIRS;
        int2 ij = pairs[p];
        const float* xb = x + b * NB_VAR * 2;
        feat[tid][0] = xb[ij.x * 2 + 0];
        feat[tid][1] = xb[ij.x * 2 + 1];
        feat[tid][2] = xb[ij.y * 2 + 0];
        feat[tid][3] = xb[ij.y * 2 + 1];
    }
    __syncthreads();
    float4 w = ((const float4*)w_in)[tid];
    float bi = b_in[tid];
    float s = 0.f, s2 = 0.f;
    for (int t = 0; t < 54; t++) {
        float v = fmaf(feat[t][0], w.x, fmaf(feat[t][1], w.y,
                  fmaf(feat[t][2], w.z, fmaf(feat[t][3], w.w, bi))));
        v = fmaxf(v, 0.f);
        h0[(size_t)(r0 + t) * HID + tid] = v;
        s += v; s2 += v * v;
    }
    atomicAdd(&st[tid], s);
    atomicAdd(&st[HID + tid], s2);
}

// ---------------- MFMA GEMM: Y = relu(bn(X)) @ W^T + bias (+res), col stats ----------------
// X: RTOT x 256 fp32. Wb: 256 x 256 bf16 row-major. Y: RTOT x 256.
__global__ __launch_bounds__(256) void k_gemm(
        const float* __restrict__ X, const float* __restrict__ stin,
        const float* __restrict__ g, const float* __restrict__ beta,
        const ushort* __restrict__ Wb, const float* __restrict__ bias,
        const float* __restrict__ res, float* __restrict__ Y,
        float* __restrict__ stout) {
    __shared__ ushort sA[BM * LDST];
    __shared__ ushort sB[BN * LDST];
    __shared__ float sS[HID], sT[HID];
    __shared__ float sCS[2][BN], sCQ[2][BN];

    int tid = threadIdx.x;
    {
        float sum = stin[tid], sq = stin[HID + tid];
        float m = sum * (1.f / RTOT);
        float v = sq * (1.f / RTOT) - m * m;
        float sc = g[tid] * rsqrtf(v + EPS);
        sS[tid] = sc;
        sT[tid] = fmaf(-m, sc, beta[tid]);
    }
    __syncthreads();

    int bm0 = blockIdx.x * BM;
    int bn0 = blockIdx.y * BN;
    int lane = tid & 63, wid = tid >> 6;
    int wr = wid >> 1, wc = wid & 1;

    f32x4 acc[4][2] = {};

    for (int k0 = 0; k0 < HID; k0 += BK) {
        // stage A (BN+ReLU+bf16): 128 rows x 32 k
#pragma unroll
        for (int l = 0; l < 4; l++) {
            int lin = tid + l * 256;
            int row = lin >> 3, kv = lin & 7;
            int gr = bm0 + row; gr = gr < RTOT ? gr : RTOT - 1;
            int k = k0 + kv * 4;
            float4 a = *(const float4*)(X + (size_t)gr * HID + k);
            a.x = fmaxf(fmaf(a.x, sS[k + 0], sT[k + 0]), 0.f);
            a.y = fmaxf(fmaf(a.y, sS[k + 1], sT[k + 1]), 0.f);
            a.z = fmaxf(fmaf(a.z, sS[k + 2], sT[k + 2]), 0.f);
            a.w = fmaxf(fmaf(a.w, sS[k + 3], sT[k + 3]), 0.f);
            uint2 pk = make_uint2(pk2(a.x, a.y), pk2(a.z, a.w));
            *(uint2*)&sA[row * LDST + kv * 4] = pk;
        }
        // stage B: 64 rows x 32 k bf16 (1x 16B per thread)
        {
            int row = tid >> 2, c = tid & 3;
            uint4 wv = *(const uint4*)(Wb + (size_t)(bn0 + row) * HID + k0 + c * 8);
            *(uint4*)&sB[row * LDST + c * 8] = wv;
        }
        __syncthreads();
        bf8 af[4], bf[2];
#pragma unroll
        for (int m = 0; m < 4; m++)
            af[m] = *(const bf8*)&sA[(wr * 64 + m * 16 + (lane & 15)) * LDST + (lane >> 4) * 8];
#pragma unroll
        for (int n = 0; n < 2; n++)
            bf[n] = *(const bf8*)&sB[(wc * 32 + n * 16 + (lane & 15)) * LDST + (lane >> 4) * 8];
#pragma unroll
        for (int m = 0; m < 4; m++)
#pragma unroll
            for (int n = 0; n < 2; n++)
                acc[m][n] = __builtin_amdgcn_mfma_f32_16x16x32_bf16(af[m], bf[n], acc[m][n], 0, 0, 0);
        __syncthreads();
    }

    // epilogue: bias (+res), store, column stats
    int rb = bm0 + wr * 64;
    int cb = bn0 + wc * 32;
    float csum[2] = {0.f, 0.f}, csq[2] = {0.f, 0.f};
#pragma unroll
    for (int n = 0; n < 2; n++) {
        int col = cb + n * 16 + (lane & 15);
        float bv = bias[col];
#pragma unroll
        for (int m = 0; m < 4; m++) {
#pragma unroll
            for (int i = 0; i < 4; i++) {
                int r = rb + m * 16 + (lane >> 4) * 4 + i;
                if (r < RTOT) {
                    float v = acc[m][n][i] + bv;
                    if (res) v += res[(size_t)r * HID + col];
                    Y[(size_t)r * HID + col] = v;
                    csum[n] += v; csq[n] += v * v;
                }
            }
        }
    }
#pragma unroll
    for (int n = 0; n < 2; n++) {
        float s = csum[n], q = csq[n];
        s += __shfl_xor(s, 16); q += __shfl_xor(q, 16);
        s += __shfl_xor(s, 32); q += __shfl_xor(q, 32);
        if (lane < 16) {
            int lc = wc * 32 + n * 16 + lane;
            sCS[wr][lc] = s; sCQ[wr][lc] = q;
        }
    }
    __syncthreads();
    if (tid < 2 * BN) {
        int col = tid & (BN - 1), q = tid >> 6;   // BN=64
        float v = q ? (sCQ[0][col] + sCQ[1][col]) : (sCS[0][col] + sCS[1][col]);
        atomicAdd(&stout[q * HID + bn0 + col], v);
    }
}

// ---------------- final GEMM (N=81) with fused symmetric scatter ----------------
__global__ __launch_bounds__(256) void k_gout(
        const float* __restrict__ X, const float* __restrict__ stin,
        const float* __restrict__ g, const float* __restrict__ beta,
        const ushort* __restrict__ Wb, const float* __restrict__ b_out,
        const int2* __restrict__ pairs, float* __restrict__ out) {
    __shared__ ushort sA[BM * LDST];
    __shared__ ushort sB[BN * LDST];
    __shared__ float sS[HID], sT[HID];

    int tid = threadIdx.x;
    {
        float sum = stin[tid], sq = stin[HID + tid];
        float m = sum * (1.f / RTOT);
        float v = sq * (1.f / RTOT) - m * m;
        float sc = g[tid] * rsqrtf(v + EPS);
        sS[tid] = sc;
        sT[tid] = fmaf(-m, sc, beta[tid]);
    }
    __syncthreads();

    int bm0 = blockIdx.x * BM;
    int bn0 = blockIdx.y * BN;
    int lane = tid & 63, wid = tid >> 6;
    int wr = wid >> 1, wc = wid & 1;

    f32x4 acc[4][2] = {};

    for (int k0 = 0; k0 < HID; k0 += BK) {
#pragma unroll
        for (int l = 0; l < 4; l++) {
            int lin = tid + l * 256;
            int row = lin >> 3, kv = lin & 7;
            int gr = bm0 + row; gr = gr < RTOT ? gr : RTOT - 1;
            int k = k0 + kv * 4;
            float4 a = *(const float4*)(X + (size_t)gr * HID + k);
            a.x = fmaxf(fmaf(a.x, sS[k + 0], sT[k + 0]), 0.f);
            a.y = fmaxf(fmaf(a.y, sS[k + 1], sT[k + 1]), 0.f);
            a.z = fmaxf(fmaf(a.z, sS[k + 2], sT[k + 2]), 0.f);
            a.w = fmaxf(fmaf(a.w, sS[k + 3], sT[k + 3]), 0.f);
            uint2 pk = make_uint2(pk2(a.x, a.y), pk2(a.z, a.w));
            *(uint2*)&sA[row * LDST + kv * 4] = pk;
        }
        {
            int row = tid >> 2, c = tid & 3;
            int gn = bn0 + row; gn = gn < 81 ? gn : 80;
            uint4 wv = *(const uint4*)(Wb + (size_t)gn * HID + k0 + c * 8);
            *(uint4*)&sB[row * LDST + c * 8] = wv;
        }
        __syncthreads();
        bf8 af[4], bf[2];
#pragma unroll
        for (int m = 0; m < 4; m++)
            af[m] = *(const bf8*)&sA[(wr * 64 + m * 16 + (lane & 15)) * LDST + (lane >> 4) * 8];
#pragma unroll
        for (int n = 0; n < 2; n++)
            bf[n] = *(const bf8*)&sB[(wc * 32 + n * 16 + (lane & 15)) * LDST + (lane >> 4) * 8];
#pragma unroll
        for (int m = 0; m < 4; m++)
#pragma unroll
            for (int n = 0; n < 2; n++)
                acc[m][n] = __builtin_amdgcn_mfma_f32_16x16x32_bf16(af[m], bf[n], acc[m][n], 0, 0, 0);
        __syncthreads();
    }

    // epilogue: bias + symmetric scatter
    int rb = bm0 + wr * 64;
    int cb = bn0 + wc * 32;
    int tcol[2], ttr[2]; float bv[2]; bool tok[2];
#pragma unroll
    for (int n = 0; n < 2; n++) {
        int t = cb + n * 16 + (lane & 15);
        tok[n] = t < 81;
        int tc = tok[n] ? t : 0;
        tcol[n] = tc;
        int gi = tc / 9, gj = tc - gi * 9;
        ttr[n] = gj * 9 + gi;
        bv[n] = b_out[tc];
    }
#pragma unroll
    for (int m = 0; m < 4; m++) {
#pragma unroll
        for (int i = 0; i < 4; i++) {
            int r = rb + m * 16 + (lane >> 4) * 4 + i;
            if (r >= RTOT) continue;
            int b = r / PAIRS, p = r - b * PAIRS;
            int2 ij = pairs[p];
            size_t base1 = ((size_t)(b * NB_VAR + ij.x) * NB_VAR + ij.y) * 81;
            size_t base2 = ((size_t)(b * NB_VAR + ij.y) * NB_VAR + ij.x) * 81;
#pragma unroll
            for (int n = 0; n < 2; n++) {
                if (!tok[n]) continue;
                float v = acc[m][n][i] + bv[n];
                out[base1 + tcol[n]] = v;
                out[base2 + ttr[n]] = v;
            }
        }
    }
}

extern "C" void kernel_launch(void* const* d_in, const int* in_sizes, int n_in,
                              void* d_out, int out_size, void* d_ws, size_t ws_size,
                              hipStream_t stream) {
    const float* x     = (const float*)d_in[0];
    const float* w_in  = (const float*)d_in[1];
    const float* b_in  = (const float*)d_in[2];
    const float* g1    = (const float*)d_in[3];
    const float* beta1 = (const float*)d_in[4];
    const float* w1    = (const float*)d_in[5];
    const float* bias1 = (const float*)d_in[6];
    const float* g2    = (const float*)d_in[7];
    const float* beta2 = (const float*)d_in[8];
    const float* w2    = (const float*)d_in[9];
    const float* bias2 = (const float*)d_in[10];
    const float* fg    = (const float*)d_in[11];
    const float* fbeta = (const float*)d_in[12];
    const float* w_out = (const float*)d_in[13];
    const float* b_out = (const float*)d_in[14];
    float* out = (float*)d_out;

    float* buf0  = (float*)d_ws;
    float* buf1  = buf0 + (size_t)RTOT * HID;
    float* buf2  = buf1 + (size_t)RTOT * HID;
    float* stats = buf2 + (size_t)RTOT * HID;
    int2*  pairs = (int2*)(stats + 5 * 512);
    ushort* wbf  = (ushort*)(pairs + PAIRS);
    // wbf layout: w1_0 @0, w1_1 @65536, w2_0 @131072, w2_1 @196608, w_out @262144

    k_misc<<<(4 * NB_VAR * 81 + 255) / 256, 256, 0, stream>>>(pairs, stats, out);
    k_wconv<<<(262144 + 81 * 256 + 255) / 256, 256, 0, stream>>>(w1, w2, w_out, wbf);
    k_in<<<240, 256, 0, stream>>>(x, w_in, b_in, pairs, buf0, stats + 0 * 512);

    dim3 gmid((RTOT + BM - 1) / BM, HID / BN);   // (102, 4)
    dim3 gout((RTOT + BM - 1) / BM, 2);          // (102, 2) -> cols 0-63, 64-80

    k_gemm<<<gmid, 256, 0, stream>>>(buf0, stats + 0 * 512, g1, beta1,
                                     wbf + 0 * 65536, bias1, nullptr, buf1, stats + 1 * 512);
    k_gemm<<<gmid, 256, 0, stream>>>(buf1, stats + 1 * 512, g2, beta2,
                                     wbf + 2 * 65536, bias2, buf0, buf2, stats + 2 * 512);
    k_gemm<<<gmid, 256, 0, stream>>>(buf2, stats + 2 * 512, g1 + HID, beta1 + HID,
                                     wbf + 1 * 65536, bias1 + HID, nullptr, buf1, stats + 3 * 512);
    k_gemm<<<gmid, 256, 0, stream>>>(buf1, stats + 3 * 512, g2 + HID, beta2 + HID,
                                     wbf + 3 * 65536, bias2 + HID, buf2, buf0, stats + 4 * 512);
    k_gout<<<gout, 256, 0, stream>>>(buf0, stats + 4 * 512, fg, fbeta,
                                     wbf + 4 * 65536, b_out, pairs, out);
}